// Round 6
// baseline (617.288 us; speedup 1.0000x reference)
//
#include <hip/hip_runtime.h>
#include <hip/hip_bf16.h>
#include <cstddef>
#include <cstdint>

// GraphSAGE 2-layer forward for MI355X (gfx950).
//
// Round 6 (6 dispatches total):
//   prep        : zero cnt01 + build WT0/WT1 (bf16, [n][512] self||neigh)
//   edge_hist01 : histogram both layers' dst into cnt01
//   scan_csr    : single-block (1024t) int4 scan -> offs01, cursor(=cnt01)
//   edge_scatter01 : CSR edge lists (layer-0 rows pre-resolved via input_nodes)
//   sage_fused<256> : per-64-row block: gather+mean into LDS tiles, then
//                     MFMA GEMM  h1 = relu([self|mean] @ WT0^T + b0)
//   sage_fused<128> : same for layer 1 -> out

#define HID 256
#define N1 65536
#define N2 4096
#define NC (N1 + N2)          // 69632 = 17*4096

using f32x4  = __attribute__((ext_vector_type(4))) float;
using bf16x8 = __attribute__((ext_vector_type(8))) short;
using u16x8  = __attribute__((ext_vector_type(8))) unsigned short;

static __device__ __forceinline__ ushort f2bf(float f) {
    union { float f; unsigned u; } v; v.f = f;
    unsigned r = v.u + 0x7FFF + ((v.u >> 16) & 1);   // RNE
    return (ushort)(r >> 16);
}
static __device__ __forceinline__ float bf2f(ushort h) {
    union { unsigned u; float f; } v; v.u = ((unsigned)h) << 16;
    return v.f;
}

// ---------------- prep: zero counters + W pre-transpose ----------------
__global__ __launch_bounds__(256) void prep(
    const float* __restrict__ Ws0, const float* __restrict__ Wn0,
    const float* __restrict__ Ws1, const float* __restrict__ Wn1,
    ushort* __restrict__ WT0, ushort* __restrict__ WT1,
    int* __restrict__ cnt01)
{
    int i = blockIdx.x * 256 + threadIdx.x;
    if (i < NC) cnt01[i] = 0;
    if (i < 256 * 512) {
        int n = i >> 9, k = i & 511;
        float v = (k < HID) ? Ws0[(size_t)k * 256 + n] : Wn0[(size_t)(k - HID) * 256 + n];
        WT0[i] = f2bf(v);
    } else {
        int j = i - 256 * 512;
        int n = j >> 9, k = j & 511;
        float v = (k < HID) ? Ws1[(size_t)k * 128 + n] : Wn1[(size_t)(k - HID) * 128 + n];
        WT1[j] = f2bf(v);
    }
}

// ---------------- fused CSR build ----------------
__global__ __launch_bounds__(256) void edge_hist01(
    const int* __restrict__ dst0, const int* __restrict__ dst1,
    int* __restrict__ cnt01, int E0, int E1)
{
    int i = blockIdx.x * 256 + threadIdx.x;
    if (i < E0) atomicAdd(&cnt01[dst0[i]], 1);
    else if (i < E0 + E1) atomicAdd(&cnt01[N1 + dst1[i - E0]], 1);
}

// single block, 1024 threads: exclusive scan of cnt01[0..NC) -> offs, and
// cursor (in-place into cnt). 17 passes of int4, shfl wave-scan + carry.
__global__ __launch_bounds__(1024) void scan_csr(
    int* __restrict__ cnt, int* __restrict__ offs)
{
    __shared__ int wsum[16];
    const int t = threadIdx.x;
    const int lane = t & 63, wid = t >> 6;
    int carry = 0;
    #pragma unroll
    for (int p = 0; p < NC / 4096; ++p) {
        int4 v = ((const int4*)cnt)[p * 1024 + t];
        int tsum = v.x + v.y + v.z + v.w;
        int inc = tsum;
        #pragma unroll
        for (int d = 1; d < 64; d <<= 1) {
            int y = __shfl_up(inc, (unsigned)d, 64);
            if (lane >= d) inc += y;
        }
        if (lane == 63) wsum[wid] = inc;
        __syncthreads();
        int wbase = 0, tot = 0;
        #pragma unroll
        for (int j = 0; j < 16; ++j) {
            int s = wsum[j];
            if (j < wid) wbase += s;
            tot += s;
        }
        int excl = carry + wbase + (inc - tsum);
        int4 o;
        o.x = excl;
        o.y = o.x + v.x;
        o.z = o.y + v.y;
        o.w = o.z + v.z;
        ((int4*)offs)[p * 1024 + t] = o;
        ((int4*)cnt)[p * 1024 + t] = o;        // cursor for scatter
        carry += tot;
        __syncthreads();                        // wsum reuse
    }
    if (t == 0) offs[NC] = carry;
}

__global__ __launch_bounds__(256) void edge_scatter01(
    const int* __restrict__ src0, const int* __restrict__ dst0,
    const int* __restrict__ src1, const int* __restrict__ dst1,
    const int* __restrict__ node_idx,
    int* __restrict__ cursor, int* __restrict__ edge_rows, int E0, int E1)
{
    int i = blockIdx.x * 256 + threadIdx.x;
    if (i < E0) {
        int pos = atomicAdd(&cursor[dst0[i]], 1);
        edge_rows[pos] = node_idx[src0[i]];
    } else if (i < E0 + E1) {
        int e = i - E0;
        int pos = atomicAdd(&cursor[N1 + dst1[e]], 1);
        edge_rows[pos] = src1[e];
    }
}

// ---------------- fused gather-mean + bf16 MFMA GEMM ----------------
// Block = 64 dst rows. Phase 1: gather/mean -> LDS meanS (4 swizzled K-tiles).
// Phase 2: Out[64][BN] = [self|mean](64x512) @ WT^T + bias (+ReLU).
// SELF_F32: table rows f32[256] (embed), else bf16[256] (h1).
template<int BN, bool RELU, bool GATHER, bool SELF_F32, bool OUT_BF16>
__global__ __launch_bounds__(256) void sage_fused(
    const void* __restrict__ table,
    const int* __restrict__ idx,          // input_nodes (GATHER) or unused
    const int* __restrict__ offs,         // absolute CSR offsets for this layer
    const int* __restrict__ edge_rows,    // combined edge list (absolute pos)
    const ushort* __restrict__ WT,        // [BN][512] bf16
    const float* __restrict__ bias,       // [BN]
    void* __restrict__ Out)               // [M][BN] bf16 or f32
{
    constexpr int BM = 64, BK = 64;
    constexpr int WN = BN / 64;           // waves along N (4 or 2)
    constexpr int WM = 4 / WN;            // waves along M (1 or 2)
    constexpr int M_FR = (BM / WM) / 16;  // m-frags per wave (4 or 2)

    __shared__ __align__(16) ushort As[BM * BK];          // 8 KB
    __shared__ __align__(16) ushort Bs[BN * BK];          // 32/16 KB
    __shared__ __align__(16) ushort meanS[4][BM * BK];    // 32 KB

    const int t = threadIdx.x;
    const int brow = blockIdx.x * BM;
    const int w = t >> 6, l = t & 63;
    const int wc = (w % WN) * 64;
    const int wr = (w / WN) * (BM / WM);
    const int l15 = l & 15, l4 = l >> 4;

    f32x4 acc[M_FR][4] = {};
    f32x4 af[4];
    u16x8 ah[2];
    u16x8 bh[BN / 32];

    auto load_step = [&](int k0) {
        if (k0 < HID) {
            if (SELF_F32) {
                #pragma unroll
                for (int i = 0; i < 4; ++i) {
                    int li = t + i * 256; int r = li >> 4; int k4 = (li & 15) << 2;
                    size_t rg = GATHER ? (size_t)idx[brow + r] : (size_t)(brow + r);
                    af[i] = *(const f32x4*)((const float*)table + rg * HID + k0 + k4);
                }
            } else {
                #pragma unroll
                for (int i = 0; i < 2; ++i) {
                    int li = t + i * 256; int r = li >> 3; int k8 = (li & 7) << 3;
                    size_t rg = GATHER ? (size_t)idx[brow + r] : (size_t)(brow + r);
                    ah[i] = *(const u16x8*)((const ushort*)table + rg * HID + k0 + k8);
                }
            }
        }
        #pragma unroll
        for (int i = 0; i < BN / 32; ++i) {
            int li = t + i * 256; int n = li >> 3; int k8 = (li & 7) << 3;
            bh[i] = *(const u16x8*)(WT + (size_t)n * 512 + k0 + k8);
        }
    };

    auto store_step = [&](int k0) {
        if (k0 < HID) {
            if (SELF_F32) {
                #pragma unroll
                for (int i = 0; i < 4; ++i) {
                    int li = t + i * 256; int r = li >> 4; int k4 = (li & 15) << 2;
                    ushort4 h;
                    h.x = f2bf(af[i].x); h.y = f2bf(af[i].y);
                    h.z = f2bf(af[i].z); h.w = f2bf(af[i].w);
                    *(ushort4*)&As[(r * BK + k4) ^ ((r & 7) << 3)] = h;
                }
            } else {
                #pragma unroll
                for (int i = 0; i < 2; ++i) {
                    int li = t + i * 256; int r = li >> 3; int k8 = (li & 7) << 3;
                    *(u16x8*)&As[(r * BK + k8) ^ ((r & 7) << 3)] = ah[i];
                }
            }
        }
        #pragma unroll
        for (int i = 0; i < BN / 32; ++i) {
            int li = t + i * 256; int n = li >> 3; int k8 = (li & 7) << 3;
            *(u16x8*)&Bs[(n * BK + k8) ^ ((n & 7) << 3)] = bh[i];
        }
    };

    // issue first K-step's global loads early (latency hides under gather)
    load_step(0);

    // ---- phase 1: gather + mean, 16 dst rows per wave ----
    for (int i = 0; i < 16; ++i) {
        int row = w * 16 + i;                 // local row in [0,64)
        int beg = offs[brow + row], end = offs[brow + row + 1];
        float a0 = 0.f, a1 = 0.f, a2 = 0.f, a3 = 0.f;
        int e = beg;
        while (e < end) {
            int cnt = end - e; cnt = cnt > 8 ? 8 : cnt;
            int myrow = 0;
            if (l < cnt) myrow = edge_rows[e + l];
            f32x4  vf[8];
            ushort4 vh[8];
            #pragma unroll
            for (int j = 0; j < 8; ++j) {
                if (j < cnt) {                 // wave-uniform predicate
                    int r = __shfl(myrow, j);
                    if (SELF_F32)
                        vf[j] = *((const f32x4*)((const float*)table + (size_t)r * HID) + l);
                    else
                        vh[j] = *((const ushort4*)((const ushort*)table + (size_t)r * HID) + l);
                }
            }
            #pragma unroll
            for (int j = 0; j < 8; ++j) {
                if (j < cnt) {
                    if (SELF_F32) { a0 += vf[j].x; a1 += vf[j].y; a2 += vf[j].z; a3 += vf[j].w; }
                    else { a0 += bf2f(vh[j].x); a1 += bf2f(vh[j].y); a2 += bf2f(vh[j].z); a3 += bf2f(vh[j].w); }
                }
            }
            e += cnt;
        }
        float inv = 1.0f / (float)max(end - beg, 1);
        ushort4 o;
        o.x = f2bf(a0 * inv); o.y = f2bf(a1 * inv);
        o.z = f2bf(a2 * inv); o.w = f2bf(a3 * inv);
        // lane l covers k = l*4..l*4+3 of 256 -> tile l>>4, local k (l&15)*4
        *(ushort4*)&meanS[l4][(row * BK + l15 * 4) ^ ((row & 7) << 3)] = o;
    }
    __syncthreads();

    // ---- phase 2: MFMA over 8 K-steps ----
    store_step(0);
    __syncthreads();

    for (int k0 = 0; k0 < 2 * HID; k0 += BK) {
        int kn = k0 + BK;
        if (kn < 2 * HID) load_step(kn);      // reg prefetch overlaps MFMA

        const ushort* abase = (k0 < HID) ? As : meanS[(k0 - HID) >> 6];
        #pragma unroll
        for (int kk = 0; kk < 2; ++kk) {
            int koff = kk * 32 + l4 * 8;
            bf16x8 a[M_FR], b[4];
            #pragma unroll
            for (int m = 0; m < M_FR; ++m) {
                int r = wr + m * 16 + l15;
                a[m] = *(const bf16x8*)&abase[(r * BK + koff) ^ ((r & 7) << 3)];
            }
            #pragma unroll
            for (int n = 0; n < 4; ++n) {
                int c = wc + n * 16 + l15;
                b[n] = *(const bf16x8*)&Bs[(c * BK + koff) ^ ((c & 7) << 3)];
            }
            #pragma unroll
            for (int m = 0; m < M_FR; ++m)
                #pragma unroll
                for (int n = 0; n < 4; ++n)
                    acc[m][n] = __builtin_amdgcn_mfma_f32_16x16x32_bf16(
                        a[m], b[n], acc[m][n], 0, 0, 0);
        }
        __syncthreads();
        if (kn < 2 * HID) store_step(kn);
        __syncthreads();
    }

    // ---- epilogue: D[(l>>4)*4+r][l&15] per frag ----
    #pragma unroll
    for (int m = 0; m < M_FR; ++m) {
        #pragma unroll
        for (int n = 0; n < 4; ++n) {
            int col = wc + n * 16 + l15;
            float bv = bias[col];
            #pragma unroll
            for (int r = 0; r < 4; ++r) {
                int row = brow + wr + m * 16 + l4 * 4 + r;
                float v = acc[m][n][r] + bv;
                if (RELU) v = fmaxf(v, 0.f);
                if (OUT_BF16) ((ushort*)Out)[(size_t)row * BN + col] = f2bf(v);
                else          ((float*)Out)[(size_t)row * BN + col] = v;
            }
        }
    }
}

extern "C" void kernel_launch(void* const* d_in, const int* in_sizes, int n_in,
                              void* d_out, int out_size, void* d_ws, size_t ws_size,
                              hipStream_t stream) {
    const int*   input_nodes = (const int*)d_in[0];
    const int*   src0        = (const int*)d_in[1];
    const int*   dst0        = (const int*)d_in[2];
    const int*   src1        = (const int*)d_in[3];
    const int*   dst1        = (const int*)d_in[4];
    const float* embed       = (const float*)d_in[7];
    const float* W_self0     = (const float*)d_in[8];
    const float* W_neigh0    = (const float*)d_in[9];
    const float* b0          = (const float*)d_in[10];
    const float* W_self1     = (const float*)d_in[11];
    const float* W_neigh1    = (const float*)d_in[12];
    const float* b1          = (const float*)d_in[13];
    float*       out         = (float*)d_out;

    const int E0 = in_sizes[1];          // 1048576
    const int E1 = in_sizes[3];          // 65536

    // -------- workspace layout --------
    char* ws = (char*)d_ws;
    ushort* h1      = (ushort*)(ws + ((size_t)0  << 20));  // 32 MB bf16
    int*    edges01 = (int*)  (ws + ((size_t)32 << 20));   // (E0+E1)*4 ~ 4.25 MB
    int*    cnt01   = (int*)  (ws + ((size_t)40 << 20));   // 69632 ints (-> cursor)
    int*    offs01  = (int*)  (ws + ((size_t)41 << 20));   // 69633 ints
    ushort* WT0     = (ushort*)(ws + ((size_t)42 << 20));  // 256 KB
    ushort* WT1     = (ushort*)(ws + ((size_t)43 << 20));  // 128 KB

    // -------- CSR build + weight prep (4 dispatches) --------
    prep<<<768, 256, 0, stream>>>(W_self0, W_neigh0, W_self1, W_neigh1,
                                  WT0, WT1, cnt01);
    edge_hist01<<<(E0 + E1 + 255) / 256, 256, 0, stream>>>(dst0, dst1, cnt01, E0, E1);
    scan_csr<<<1, 1024, 0, stream>>>(cnt01, offs01);
    edge_scatter01<<<(E0 + E1 + 255) / 256, 256, 0, stream>>>(
        src0, dst0, src1, dst1, input_nodes, cnt01, edges01, E0, E1);

    // -------- layer 0: fused gather-mean + GEMM --------
    sage_fused<256, true, true, true, true><<<N1 / 64, 256, 0, stream>>>(
        embed, input_nodes, offs01, edges01, WT0, b0, h1);

    // -------- layer 1: fused gather-mean + GEMM --------
    sage_fused<128, false, false, false, false><<<N2 / 64, 256, 0, stream>>>(
        h1, nullptr, offs01 + N1, edges01, WT1, b1, out);
}

// Round 7
// 389.560 us; speedup vs baseline: 1.5846x; 1.5846x over previous
//
#include <hip/hip_runtime.h>
#include <hip/hip_bf16.h>
#include <cstddef>
#include <cstdint>

// GraphSAGE 2-layer forward for MI355X (gfx950).
//
// Round 7 = round 5 structure (fusion of round 6 REVERTED: 72KB-LDS fused
// kernel capped occupancy and starved the gather of MLP) plus:
//  - gather: 16-deep load pipeline (was 8); most nodes finish in one batch
//  - gather0 also emits the dst's own embed row as bf16 (selfB) so gemm0
//    A-staging is all-linear bf16 (random f32 self-gather removed from GEMM)
// 8 dispatches.

#define HID 256
#define N1 65536
#define N2 4096
#define NC (N1 + N2)          // 69632 = 17*4096

using f32x4  = __attribute__((ext_vector_type(4))) float;
using bf16x8 = __attribute__((ext_vector_type(8))) short;
using u16x8  = __attribute__((ext_vector_type(8))) unsigned short;

static __device__ __forceinline__ ushort f2bf(float f) {
    union { float f; unsigned u; } v; v.f = f;
    unsigned r = v.u + 0x7FFF + ((v.u >> 16) & 1);   // RNE
    return (ushort)(r >> 16);
}
static __device__ __forceinline__ float bf2f(ushort h) {
    union { unsigned u; float f; } v; v.u = ((unsigned)h) << 16;
    return v.f;
}

// ---------------- prep: zero counters + W pre-transpose ----------------
// WT[n][k], k in [0,512): k<256 -> W_self[k][n], else W_neigh[k-256][n]
__global__ __launch_bounds__(256) void prep(
    const float* __restrict__ Ws0, const float* __restrict__ Wn0,
    const float* __restrict__ Ws1, const float* __restrict__ Wn1,
    ushort* __restrict__ WT0, ushort* __restrict__ WT1,
    int* __restrict__ cnt01)
{
    int i = blockIdx.x * 256 + threadIdx.x;
    if (i < NC) cnt01[i] = 0;
    if (i < 256 * 512) {
        int n = i >> 9, k = i & 511;
        float v = (k < HID) ? Ws0[(size_t)k * 256 + n] : Wn0[(size_t)(k - HID) * 256 + n];
        WT0[i] = f2bf(v);
    } else {
        int j = i - 256 * 512;
        int n = j >> 9, k = j & 511;
        float v = (k < HID) ? Ws1[(size_t)k * 128 + n] : Wn1[(size_t)(k - HID) * 128 + n];
        WT1[j] = f2bf(v);
    }
}

// ---------------- fused CSR build ----------------
__global__ __launch_bounds__(256) void edge_hist01(
    const int* __restrict__ dst0, const int* __restrict__ dst1,
    int* __restrict__ cnt01, int E0, int E1)
{
    int i = blockIdx.x * 256 + threadIdx.x;
    if (i < E0) atomicAdd(&cnt01[dst0[i]], 1);
    else if (i < E0 + E1) atomicAdd(&cnt01[N1 + dst1[i - E0]], 1);
}

// single block, 1024 threads: exclusive scan of cnt01[0..NC) -> offs, and
// cursor (in-place into cnt). 17 passes of int4, shfl wave-scan + carry.
__global__ __launch_bounds__(1024) void scan_csr(
    int* __restrict__ cnt, int* __restrict__ offs)
{
    __shared__ int wsum[16];
    const int t = threadIdx.x;
    const int lane = t & 63, wid = t >> 6;
    int carry = 0;
    #pragma unroll
    for (int p = 0; p < NC / 4096; ++p) {
        int4 v = ((const int4*)cnt)[p * 1024 + t];
        int tsum = v.x + v.y + v.z + v.w;
        int inc = tsum;
        #pragma unroll
        for (int d = 1; d < 64; d <<= 1) {
            int y = __shfl_up(inc, (unsigned)d, 64);
            if (lane >= d) inc += y;
        }
        if (lane == 63) wsum[wid] = inc;
        __syncthreads();
        int wbase = 0, tot = 0;
        #pragma unroll
        for (int j = 0; j < 16; ++j) {
            int s = wsum[j];
            if (j < wid) wbase += s;
            tot += s;
        }
        int excl = carry + wbase + (inc - tsum);
        int4 o;
        o.x = excl;
        o.y = o.x + v.x;
        o.z = o.y + v.y;
        o.w = o.z + v.z;
        ((int4*)offs)[p * 1024 + t] = o;
        ((int4*)cnt)[p * 1024 + t] = o;        // cursor for scatter
        carry += tot;
        __syncthreads();                        // wsum reuse
    }
    if (t == 0) offs[NC] = carry;
}

__global__ __launch_bounds__(256) void edge_scatter01(
    const int* __restrict__ src0, const int* __restrict__ dst0,
    const int* __restrict__ src1, const int* __restrict__ dst1,
    const int* __restrict__ node_idx,
    int* __restrict__ cursor, int* __restrict__ edge_rows, int E0, int E1)
{
    int i = blockIdx.x * 256 + threadIdx.x;
    if (i < E0) {
        int pos = atomicAdd(&cursor[dst0[i]], 1);
        edge_rows[pos] = node_idx[src0[i]];
    } else if (i < E0 + E1) {
        int e = i - E0;
        int pos = atomicAdd(&cursor[N1 + dst1[e]], 1);
        edge_rows[pos] = src1[e];
    }
}

// ------- gather + mean: one wave per dst, 16-deep MLP, opt. self emit -------
// SRC_F32: table rows f32[256] (embed); else bf16[256] (h1).
// EMIT_SELF: also write selfB[w] = bf16(table[node_idx[w]]).
template<bool SRC_F32, bool EMIT_SELF>
__global__ __launch_bounds__(256) void sage_gather_mean(
    const void* __restrict__ table,
    const int* __restrict__ node_idx,
    const int* __restrict__ offs,          // absolute positions
    const int* __restrict__ edge_rows,
    ushort* __restrict__ mean_out,
    ushort* __restrict__ self_out,
    int n_dst)
{
    int w = blockIdx.x * 4 + (threadIdx.x >> 6);
    int lane = threadIdx.x & 63;
    if (w >= n_dst) return;

    // self row fetch issued first: its latency hides under the edge loop
    f32x4 sv;
    if (EMIT_SELF) {
        int r = node_idx[w];
        sv = *((const f32x4*)((const float*)table + (size_t)r * HID) + lane);
    }

    int beg = offs[w], end = offs[w + 1];
    float a0 = 0.f, a1 = 0.f, a2 = 0.f, a3 = 0.f;
    int e = beg;
    while (e < end) {
        int cnt = end - e; cnt = cnt > 16 ? 16 : cnt;
        int myrow = 0;
        if (lane < cnt) myrow = edge_rows[e + lane];
        f32x4  vf[16];
        ushort4 vh[16];
        #pragma unroll
        for (int j = 0; j < 16; ++j) {
            if (j < cnt) {                       // wave-uniform predicate
                int r = __shfl(myrow, j);
                if (SRC_F32)
                    vf[j] = *((const f32x4*)((const float*)table + (size_t)r * HID) + lane);
                else
                    vh[j] = *((const ushort4*)((const ushort*)table + (size_t)r * HID) + lane);
            }
        }
        #pragma unroll
        for (int j = 0; j < 16; ++j) {
            if (j < cnt) {
                if (SRC_F32) { a0 += vf[j].x; a1 += vf[j].y; a2 += vf[j].z; a3 += vf[j].w; }
                else { a0 += bf2f(vh[j].x); a1 += bf2f(vh[j].y); a2 += bf2f(vh[j].z); a3 += bf2f(vh[j].w); }
            }
        }
        e += cnt;
    }
    float inv = 1.0f / (float)max(end - beg, 1);
    ushort4 o;
    o.x = f2bf(a0 * inv); o.y = f2bf(a1 * inv);
    o.z = f2bf(a2 * inv); o.w = f2bf(a3 * inv);
    *((ushort4*)(mean_out + (size_t)w * HID) + lane) = o;
    if (EMIT_SELF) {
        ushort4 s;
        s.x = f2bf(sv.x); s.y = f2bf(sv.y); s.z = f2bf(sv.z); s.w = f2bf(sv.w);
        *((ushort4*)(self_out + (size_t)w * HID) + lane) = s;
    }
}

// ---------------- bf16 MFMA fused SAGE GEMM (T14 reg-prefetch) ----------------
// Out[M][BN] = [Aself | Amean] (M x 512, both bf16 linear) @ WT^T + bias (+ReLU)
// BM=64, BN=N_total, BK=64, 4 waves: 1x4 (BN=256) or 2x2 (BN=128).
template<int BN, bool RELU, bool OUT_BF16>
__global__ __launch_bounds__(256) void sage_gemm_mfma(
    const ushort* __restrict__ Aself,    // [M][256] bf16
    const ushort* __restrict__ Amean,    // [M][256] bf16
    const ushort* __restrict__ WT,       // [BN][512] bf16
    const float* __restrict__ bias,      // [BN]
    void* __restrict__ Out)              // [M][BN] bf16 or f32
{
    constexpr int BM = 64, BK = 64;
    constexpr int WN = BN / 64;
    constexpr int WM = 4 / WN;
    constexpr int M_FR = (BM / WM) / 16;

    __shared__ __align__(16) ushort As[BM * BK];
    __shared__ __align__(16) ushort Bs[BN * BK];

    const int t = threadIdx.x;
    const int brow = blockIdx.x * BM;
    const int w = t >> 6, l = t & 63;
    const int wc = (w % WN) * 64;
    const int wr = (w / WN) * (BM / WM);
    const int l15 = l & 15, l4 = l >> 4;

    f32x4 acc[M_FR][4] = {};
    u16x8 ah[2];
    u16x8 bh[BN / 32];

    auto load_step = [&](int k0) {
        const ushort* Asrc = (k0 < HID) ? Aself : Amean;
        int kb = (k0 < HID) ? k0 : (k0 - HID);
        #pragma unroll
        for (int i = 0; i < 2; ++i) {
            int li = t + i * 256; int r = li >> 3; int k8 = (li & 7) << 3;
            ah[i] = *(const u16x8*)(Asrc + (size_t)(brow + r) * HID + kb + k8);
        }
        #pragma unroll
        for (int i = 0; i < BN / 32; ++i) {
            int li = t + i * 256; int n = li >> 3; int k8 = (li & 7) << 3;
            bh[i] = *(const u16x8*)(WT + (size_t)n * 512 + k0 + k8);
        }
    };

    auto store_step = [&]() {
        #pragma unroll
        for (int i = 0; i < 2; ++i) {
            int li = t + i * 256; int r = li >> 3; int k8 = (li & 7) << 3;
            *(u16x8*)&As[(r * BK + k8) ^ ((r & 7) << 3)] = ah[i];
        }
        #pragma unroll
        for (int i = 0; i < BN / 32; ++i) {
            int li = t + i * 256; int n = li >> 3; int k8 = (li & 7) << 3;
            *(u16x8*)&Bs[(n * BK + k8) ^ ((n & 7) << 3)] = bh[i];
        }
    };

    load_step(0);
    store_step();
    __syncthreads();

    for (int k0 = 0; k0 < 2 * HID; k0 += BK) {
        int kn = k0 + BK;
        if (kn < 2 * HID) load_step(kn);       // reg prefetch overlaps MFMA

        #pragma unroll
        for (int kk = 0; kk < 2; ++kk) {
            int koff = kk * 32 + l4 * 8;
            bf16x8 a[M_FR], b[4];
            #pragma unroll
            for (int m = 0; m < M_FR; ++m) {
                int r = wr + m * 16 + l15;
                a[m] = *(const bf16x8*)&As[(r * BK + koff) ^ ((r & 7) << 3)];
            }
            #pragma unroll
            for (int n = 0; n < 4; ++n) {
                int c = wc + n * 16 + l15;
                b[n] = *(const bf16x8*)&Bs[(c * BK + koff) ^ ((c & 7) << 3)];
            }
            #pragma unroll
            for (int m = 0; m < M_FR; ++m)
                #pragma unroll
                for (int n = 0; n < 4; ++n)
                    acc[m][n] = __builtin_amdgcn_mfma_f32_16x16x32_bf16(
                        a[m], b[n], acc[m][n], 0, 0, 0);
        }
        __syncthreads();
        if (kn < 2 * HID) store_step();
        __syncthreads();
    }

    // ---- epilogue: D[(l>>4)*4+r][l&15] per frag ----
    #pragma unroll
    for (int m = 0; m < M_FR; ++m) {
        #pragma unroll
        for (int n = 0; n < 4; ++n) {
            int col = wc + n * 16 + l15;
            float bv = bias[col];
            #pragma unroll
            for (int r = 0; r < 4; ++r) {
                int row = brow + wr + m * 16 + l4 * 4 + r;
                float v = acc[m][n][r] + bv;
                if (RELU) v = fmaxf(v, 0.f);
                if (OUT_BF16) ((ushort*)Out)[(size_t)row * BN + col] = f2bf(v);
                else          ((float*)Out)[(size_t)row * BN + col] = v;
            }
        }
    }
}

extern "C" void kernel_launch(void* const* d_in, const int* in_sizes, int n_in,
                              void* d_out, int out_size, void* d_ws, size_t ws_size,
                              hipStream_t stream) {
    const int*   input_nodes = (const int*)d_in[0];
    const int*   src0        = (const int*)d_in[1];
    const int*   dst0        = (const int*)d_in[2];
    const int*   src1        = (const int*)d_in[3];
    const int*   dst1        = (const int*)d_in[4];
    const float* embed       = (const float*)d_in[7];
    const float* W_self0     = (const float*)d_in[8];
    const float* W_neigh0    = (const float*)d_in[9];
    const float* b0          = (const float*)d_in[10];
    const float* W_self1     = (const float*)d_in[11];
    const float* W_neigh1    = (const float*)d_in[12];
    const float* b1          = (const float*)d_in[13];
    float*       out         = (float*)d_out;

    const int E0 = in_sizes[1];          // 1048576
    const int E1 = in_sizes[3];          // 65536

    // -------- workspace layout --------
    char* ws = (char*)d_ws;
    ushort* h1      = (ushort*)(ws + ((size_t)0   << 20));  // 32 MB bf16
    ushort* selfB   = (ushort*)(ws + ((size_t)32  << 20));  // 32 MB bf16
    ushort* mean0   = (ushort*)(ws + ((size_t)64  << 20));  // 32 MB bf16
    int*    edges01 = (int*)  (ws + ((size_t)96  << 20));   // ~4.25 MB
    int*    cnt01   = (int*)  (ws + ((size_t)104 << 20));   // 69632 ints (-> cursor)
    int*    offs01  = (int*)  (ws + ((size_t)105 << 20));   // 69633 ints
    ushort* WT0     = (ushort*)(ws + ((size_t)106 << 20));  // 256 KB
    ushort* WT1     = (ushort*)(ws + ((size_t)107 << 20));  // 128 KB
    ushort* mean1   = (ushort*)(ws + ((size_t)108 << 20));  // 2 MB

    // -------- CSR build + weight prep (4 dispatches) --------
    prep<<<768, 256, 0, stream>>>(W_self0, W_neigh0, W_self1, W_neigh1,
                                  WT0, WT1, cnt01);
    edge_hist01<<<(E0 + E1 + 255) / 256, 256, 0, stream>>>(dst0, dst1, cnt01, E0, E1);
    scan_csr<<<1, 1024, 0, stream>>>(cnt01, offs01);
    edge_scatter01<<<(E0 + E1 + 255) / 256, 256, 0, stream>>>(
        src0, dst0, src1, dst1, input_nodes, cnt01, edges01, E0, E1);

    // ================= layer 0 =================
    sage_gather_mean<true, true><<<N1 / 4, 256, 0, stream>>>(
        embed, input_nodes, offs01, edges01, mean0, selfB, N1);
    sage_gemm_mfma<256, true, true><<<N1 / 64, 256, 0, stream>>>(
        selfB, mean0, WT0, b0, h1);

    // ================= layer 1 =================
    sage_gather_mean<false, false><<<N2 / 4, 256, 0, stream>>>(
        h1, nullptr, offs01 + N1, edges01, mean1, nullptr, N2);
    sage_gemm_mfma<128, false, false><<<N2 / 64, 256, 0, stream>>>(
        h1, mean1, WT1, b1, out);
}

// Round 8
// 348.687 us; speedup vs baseline: 1.7703x; 1.1172x over previous
//
#include <hip/hip_runtime.h>
#include <hip/hip_bf16.h>
#include <cstddef>
#include <cstdint>

// GraphSAGE 2-layer forward for MI355X (gfx950).
//
// Round 8 = round 5 structure (depth-8 gather, no selfB — r7's depth-16 and
// selfB both REVERTED as regressions) plus:
//  - gather_mean: next-batch edge-index prefetch (removes idx-load latency
//    from the inter-batch critical chain; +1 VGPR)
//  - CSR prep fused: hipMemsetAsync zeroes cnt01; WT build is tail-block
//    work in the hist kernel (one fewer dispatch, overlapped)
// 8 dispatches: memset, hist+wt, scan, scatter, gather0, gemm0, gather1, gemm1.

#define HID 256
#define N1 65536
#define N2 4096
#define NC (N1 + N2)          // 69632 = 17*4096

using f32x4  = __attribute__((ext_vector_type(4))) float;
using bf16x8 = __attribute__((ext_vector_type(8))) short;
using u16x8  = __attribute__((ext_vector_type(8))) unsigned short;

static __device__ __forceinline__ ushort f2bf(float f) {
    union { float f; unsigned u; } v; v.f = f;
    unsigned r = v.u + 0x7FFF + ((v.u >> 16) & 1);   // RNE
    return (ushort)(r >> 16);
}
static __device__ __forceinline__ float bf2f(ushort h) {
    union { unsigned u; float f; } v; v.u = ((unsigned)h) << 16;
    return v.f;
}

// -------- hist (blocks < HB) + W pre-transpose (blocks >= HB) --------
// WT[n][k], k in [0,512): k<256 -> W_self[k][n], else W_neigh[k-256][n]
__global__ __launch_bounds__(256) void hist_wt(
    const int* __restrict__ dst0, const int* __restrict__ dst1,
    const float* __restrict__ Ws0, const float* __restrict__ Wn0,
    const float* __restrict__ Ws1, const float* __restrict__ Wn1,
    ushort* __restrict__ WT0, ushort* __restrict__ WT1,
    int* __restrict__ cnt01, int E0, int E1, int HB)
{
    int b = blockIdx.x;
    int t = threadIdx.x;
    if (b < HB) {
        int i = b * 256 + t;
        if (i < E0) atomicAdd(&cnt01[dst0[i]], 1);
        else if (i < E0 + E1) atomicAdd(&cnt01[N1 + dst1[i - E0]], 1);
    } else {
        int i = (b - HB) * 256 + t;
        if (i < 256 * 512) {
            int n = i >> 9, k = i & 511;
            float v = (k < HID) ? Ws0[(size_t)k * 256 + n]
                                : Wn0[(size_t)(k - HID) * 256 + n];
            WT0[i] = f2bf(v);
        } else {
            int j = i - 256 * 512;
            int n = j >> 9, k = j & 511;
            float v = (k < HID) ? Ws1[(size_t)k * 128 + n]
                                : Wn1[(size_t)(k - HID) * 128 + n];
            WT1[j] = f2bf(v);
        }
    }
}

// single block, 1024 threads: exclusive scan of cnt01[0..NC) -> offs, and
// cursor (in-place into cnt). 17 passes of int4, shfl wave-scan + carry.
__global__ __launch_bounds__(1024) void scan_csr(
    int* __restrict__ cnt, int* __restrict__ offs)
{
    __shared__ int wsum[16];
    const int t = threadIdx.x;
    const int lane = t & 63, wid = t >> 6;
    int carry = 0;
    #pragma unroll
    for (int p = 0; p < NC / 4096; ++p) {
        int4 v = ((const int4*)cnt)[p * 1024 + t];
        int tsum = v.x + v.y + v.z + v.w;
        int inc = tsum;
        #pragma unroll
        for (int d = 1; d < 64; d <<= 1) {
            int y = __shfl_up(inc, (unsigned)d, 64);
            if (lane >= d) inc += y;
        }
        if (lane == 63) wsum[wid] = inc;
        __syncthreads();
        int wbase = 0, tot = 0;
        #pragma unroll
        for (int j = 0; j < 16; ++j) {
            int s = wsum[j];
            if (j < wid) wbase += s;
            tot += s;
        }
        int excl = carry + wbase + (inc - tsum);
        int4 o;
        o.x = excl;
        o.y = o.x + v.x;
        o.z = o.y + v.y;
        o.w = o.z + v.z;
        ((int4*)offs)[p * 1024 + t] = o;
        ((int4*)cnt)[p * 1024 + t] = o;        // cursor for scatter
        carry += tot;
        __syncthreads();                        // wsum reuse
    }
    if (t == 0) offs[NC] = carry;
}

__global__ __launch_bounds__(256) void edge_scatter01(
    const int* __restrict__ src0, const int* __restrict__ dst0,
    const int* __restrict__ src1, const int* __restrict__ dst1,
    const int* __restrict__ node_idx,
    int* __restrict__ cursor, int* __restrict__ edge_rows, int E0, int E1)
{
    int i = blockIdx.x * 256 + threadIdx.x;
    if (i < E0) {
        int pos = atomicAdd(&cursor[dst0[i]], 1);
        edge_rows[pos] = node_idx[src0[i]];
    } else if (i < E0 + E1) {
        int e = i - E0;
        int pos = atomicAdd(&cursor[N1 + dst1[e]], 1);
        edge_rows[pos] = src1[e];
    }
}

// -------- gather + mean: one wave per dst, 8-deep MLP + idx prefetch --------
// SRC_F32: table rows f32[256] (embed); else bf16[256] (h1). Output bf16.
template<bool SRC_F32>
__global__ __launch_bounds__(256) void sage_gather_mean(
    const void* __restrict__ table,
    const int* __restrict__ offs,          // absolute positions
    const int* __restrict__ edge_rows,
    ushort* __restrict__ mean_out,
    int n_dst)
{
    int w = blockIdx.x * 4 + (threadIdx.x >> 6);
    int lane = threadIdx.x & 63;
    if (w >= n_dst) return;
    int beg = offs[w], end = offs[w + 1];
    float a0 = 0.f, a1 = 0.f, a2 = 0.f, a3 = 0.f;
    int e = beg;
    int cnt = end - e; cnt = cnt > 8 ? 8 : cnt;
    int myrow = (lane < cnt) ? edge_rows[e + lane] : 0;
    while (e < end) {
        f32x4  vf[8];
        ushort4 vh[8];
        #pragma unroll
        for (int j = 0; j < 8; ++j) {
            if (j < cnt) {                       // wave-uniform predicate
                int r = __shfl(myrow, j);
                if (SRC_F32)
                    vf[j] = *((const f32x4*)((const float*)table + (size_t)r * HID) + lane);
                else
                    vh[j] = *((const ushort4*)((const ushort*)table + (size_t)r * HID) + lane);
            }
        }
        // prefetch next batch's indices before accumulating this batch
        int en = e + cnt;
        int cntn = end - en; cntn = cntn > 8 ? 8 : cntn;
        int nxt = (lane < cntn) ? edge_rows[en + lane] : 0;
        #pragma unroll
        for (int j = 0; j < 8; ++j) {
            if (j < cnt) {
                if (SRC_F32) { a0 += vf[j].x; a1 += vf[j].y; a2 += vf[j].z; a3 += vf[j].w; }
                else { a0 += bf2f(vh[j].x); a1 += bf2f(vh[j].y); a2 += bf2f(vh[j].z); a3 += bf2f(vh[j].w); }
            }
        }
        e = en; cnt = cntn; myrow = nxt;
    }
    float inv = 1.0f / (float)max(end - beg, 1);
    ushort4 o;
    o.x = f2bf(a0 * inv); o.y = f2bf(a1 * inv);
    o.z = f2bf(a2 * inv); o.w = f2bf(a3 * inv);
    *((ushort4*)(mean_out + (size_t)w * HID) + lane) = o;
}

// ---------------- bf16 MFMA fused SAGE GEMM (T14 reg-prefetch) ----------------
// Out[M][BN] = [A_self | A_mean] (M x 512) @ WT^T + bias  (+ReLU)
// BM=64, BN=N_total, BK=64, 4 waves: 1x4 (BN=256) or 2x2 (BN=128).
template<int BN, bool RELU, bool GATHER, bool SELF_F32, bool OUT_BF16>
__global__ __launch_bounds__(256) void sage_gemm_mfma(
    const void* __restrict__ Aself,      // f32 embed (SELF_F32) or bf16 h1
    const int* __restrict__ idx,         // input_nodes (GATHER) or unused
    const ushort* __restrict__ Amean,    // [M][256] bf16
    const ushort* __restrict__ WT,       // [BN][512] bf16
    const float* __restrict__ bias,      // [BN]
    void* __restrict__ Out)              // [M][BN] bf16 or f32
{
    constexpr int BM = 64, BK = 64;
    constexpr int WN = BN / 64;
    constexpr int WM = 4 / WN;
    constexpr int M_FR = (BM / WM) / 16;

    __shared__ __align__(16) ushort As[BM * BK];
    __shared__ __align__(16) ushort Bs[BN * BK];

    const int t = threadIdx.x;
    const int brow = blockIdx.x * BM;
    const int w = t >> 6, l = t & 63;
    const int wc = (w % WN) * 64;
    const int wr = (w / WN) * (BM / WM);
    const int l15 = l & 15, l4 = l >> 4;

    f32x4 acc[M_FR][4] = {};
    f32x4 af[4];
    u16x8 ah[2];
    u16x8 bh[BN / 32];

    auto load_step = [&](int k0) {
        if (SELF_F32 && k0 < HID) {
            #pragma unroll
            for (int i = 0; i < 4; ++i) {
                int li = t + i * 256; int r = li >> 4; int k4 = (li & 15) << 2;
                size_t rg = GATHER ? (size_t)idx[brow + r] : (size_t)(brow + r);
                af[i] = *(const f32x4*)((const float*)Aself + rg * HID + k0 + k4);
            }
        } else {
            #pragma unroll
            for (int i = 0; i < 2; ++i) {
                int li = t + i * 256; int r = li >> 3; int k8 = (li & 7) << 3;
                const ushort* sp;
                if (k0 < HID) {
                    size_t rg = GATHER ? (size_t)idx[brow + r] : (size_t)(brow + r);
                    sp = (const ushort*)Aself + rg * HID + k0 + k8;
                } else {
                    sp = Amean + (size_t)(brow + r) * HID + (k0 - HID) + k8;
                }
                ah[i] = *(const u16x8*)sp;
            }
        }
        #pragma unroll
        for (int i = 0; i < BN / 32; ++i) {
            int li = t + i * 256; int n = li >> 3; int k8 = (li & 7) << 3;
            bh[i] = *(const u16x8*)(WT + (size_t)n * 512 + k0 + k8);
        }
    };

    auto store_step = [&](int k0) {
        if (SELF_F32 && k0 < HID) {
            #pragma unroll
            for (int i = 0; i < 4; ++i) {
                int li = t + i * 256; int r = li >> 4; int k4 = (li & 15) << 2;
                ushort4 h;
                h.x = f2bf(af[i].x); h.y = f2bf(af[i].y);
                h.z = f2bf(af[i].z); h.w = f2bf(af[i].w);
                *(ushort4*)&As[(r * BK + k4) ^ ((r & 7) << 3)] = h;
            }
        } else {
            #pragma unroll
            for (int i = 0; i < 2; ++i) {
                int li = t + i * 256; int r = li >> 3; int k8 = (li & 7) << 3;
                *(u16x8*)&As[(r * BK + k8) ^ ((r & 7) << 3)] = ah[i];
            }
        }
        #pragma unroll
        for (int i = 0; i < BN / 32; ++i) {
            int li = t + i * 256; int n = li >> 3; int k8 = (li & 7) << 3;
            *(u16x8*)&Bs[(n * BK + k8) ^ ((n & 7) << 3)] = bh[i];
        }
    };

    load_step(0);
    store_step(0);
    __syncthreads();

    for (int k0 = 0; k0 < 2 * HID; k0 += BK) {
        int kn = k0 + BK;
        if (kn < 2 * HID) load_step(kn);       // reg prefetch overlaps MFMA

        #pragma unroll
        for (int kk = 0; kk < 2; ++kk) {
            int koff = kk * 32 + l4 * 8;
            bf16x8 a[M_FR], b[4];
            #pragma unroll
            for (int m = 0; m < M_FR; ++m) {
                int r = wr + m * 16 + l15;
                a[m] = *(const bf16x8*)&As[(r * BK + koff) ^ ((r & 7) << 3)];
            }
            #pragma unroll
            for (int n = 0; n < 4; ++n) {
                int c = wc + n * 16 + l15;
                b[n] = *(const bf16x8*)&Bs[(c * BK + koff) ^ ((c & 7) << 3)];
            }
            #pragma unroll
            for (int m = 0; m < M_FR; ++m)
                #pragma unroll
                for (int n = 0; n < 4; ++n)
                    acc[m][n] = __builtin_amdgcn_mfma_f32_16x16x32_bf16(
                        a[m], b[n], acc[m][n], 0, 0, 0);
        }
        __syncthreads();
        if (kn < 2 * HID) store_step(kn);
        __syncthreads();
    }

    // ---- epilogue: D[(l>>4)*4+r][l&15] per frag ----
    #pragma unroll
    for (int m = 0; m < M_FR; ++m) {
        #pragma unroll
        for (int n = 0; n < 4; ++n) {
            int col = wc + n * 16 + l15;
            float bv = bias[col];
            #pragma unroll
            for (int r = 0; r < 4; ++r) {
                int row = brow + wr + m * 16 + l4 * 4 + r;
                float v = acc[m][n][r] + bv;
                if (RELU) v = fmaxf(v, 0.f);
                if (OUT_BF16) ((ushort*)Out)[(size_t)row * BN + col] = f2bf(v);
                else          ((float*)Out)[(size_t)row * BN + col] = v;
            }
        }
    }
}

extern "C" void kernel_launch(void* const* d_in, const int* in_sizes, int n_in,
                              void* d_out, int out_size, void* d_ws, size_t ws_size,
                              hipStream_t stream) {
    const int*   input_nodes = (const int*)d_in[0];
    const int*   src0        = (const int*)d_in[1];
    const int*   dst0        = (const int*)d_in[2];
    const int*   src1        = (const int*)d_in[3];
    const int*   dst1        = (const int*)d_in[4];
    const float* embed       = (const float*)d_in[7];
    const float* W_self0     = (const float*)d_in[8];
    const float* W_neigh0    = (const float*)d_in[9];
    const float* b0          = (const float*)d_in[10];
    const float* W_self1     = (const float*)d_in[11];
    const float* W_neigh1    = (const float*)d_in[12];
    const float* b1          = (const float*)d_in[13];
    float*       out         = (float*)d_out;

    const int E0 = in_sizes[1];          // 1048576
    const int E1 = in_sizes[3];          // 65536

    // -------- workspace layout --------
    char* ws = (char*)d_ws;
    ushort* mean0   = (ushort*)(ws + ((size_t)0  << 20));  // 32 MB bf16
    ushort* h1      = (ushort*)(ws + ((size_t)32 << 20));  // 32 MB bf16
    int*    edges01 = (int*)  (ws + ((size_t)64 << 20));   // ~4.25 MB
    int*    cnt01   = (int*)  (ws + ((size_t)70 << 20));   // 69632 ints (-> cursor)
    int*    offs01  = (int*)  (ws + ((size_t)71 << 20));   // 69633 ints
    ushort* WT0     = (ushort*)(ws + ((size_t)72 << 20));  // 256 KB
    ushort* WT1     = (ushort*)(ws + ((size_t)73 << 20));  // 128 KB
    ushort* mean1   = (ushort*)(ws + ((size_t)74 << 20));  // 2 MB

    // -------- CSR build + weight prep --------
    const int HB = (E0 + E1 + 255) / 256;                  // hist blocks
    hipMemsetAsync(cnt01, 0, (size_t)NC * 4, stream);
    hist_wt<<<HB + 768, 256, 0, stream>>>(
        dst0, dst1, W_self0, W_neigh0, W_self1, W_neigh1,
        WT0, WT1, cnt01, E0, E1, HB);
    scan_csr<<<1, 1024, 0, stream>>>(cnt01, offs01);
    edge_scatter01<<<HB, 256, 0, stream>>>(
        src0, dst0, src1, dst1, input_nodes, cnt01, edges01, E0, E1);

    // ================= layer 0 =================
    sage_gather_mean<true><<<N1 / 4, 256, 0, stream>>>(
        embed, offs01, edges01, mean0, N1);
    sage_gemm_mfma<256, true, true, true, true><<<N1 / 64, 256, 0, stream>>>(
        embed, input_nodes, mean0, WT0, b0, h1);

    // ================= layer 1 =================
    sage_gather_mean<false><<<N2 / 4, 256, 0, stream>>>(
        h1, offs01 + N1, edges01, mean1, N2);
    sage_gemm_mfma<128, false, false, false, false><<<N2 / 64, 256, 0, stream>>>(
        h1, nullptr, mean1, WT1, b1, out);
}

// Round 9
// 339.192 us; speedup vs baseline: 1.8199x; 1.0280x over previous
//
#include <hip/hip_runtime.h>
#include <hip/hip_bf16.h>
#include <cstddef>
#include <cstdint>

// GraphSAGE 2-layer forward for MI355X (gfx950).
//
// Round 9 = round 5 structure with ONE attributable change:
//  - scan: single-block 17-pass scan_csr (16 waves on 1 CU, ~20-30us of
//    whole-GPU serialization) replaced by 3-phase parallel scan
//    (272-block chunk scan -> 1-block totals scan -> 272-block add).
//  - gather: exact r5 form (depth-8, no idx prefetch - r8 neutral/negative)
//  - hist_wt/memset kept from r8 (equivalent to r5's prep+hist)
// 10 dispatches.

#define HID 256
#define N1 65536
#define N2 4096
#define NC (N1 + N2)          // 69632 = 272*256

using f32x4  = __attribute__((ext_vector_type(4))) float;
using bf16x8 = __attribute__((ext_vector_type(8))) short;
using u16x8  = __attribute__((ext_vector_type(8))) unsigned short;

static __device__ __forceinline__ ushort f2bf(float f) {
    union { float f; unsigned u; } v; v.f = f;
    unsigned r = v.u + 0x7FFF + ((v.u >> 16) & 1);   // RNE
    return (ushort)(r >> 16);
}
static __device__ __forceinline__ float bf2f(ushort h) {
    union { unsigned u; float f; } v; v.u = ((unsigned)h) << 16;
    return v.f;
}

// -------- hist (blocks < HB) + W pre-transpose (blocks >= HB) --------
// WT[n][k], k in [0,512): k<256 -> W_self[k][n], else W_neigh[k-256][n]
__global__ __launch_bounds__(256) void hist_wt(
    const int* __restrict__ dst0, const int* __restrict__ dst1,
    const float* __restrict__ Ws0, const float* __restrict__ Wn0,
    const float* __restrict__ Ws1, const float* __restrict__ Wn1,
    ushort* __restrict__ WT0, ushort* __restrict__ WT1,
    int* __restrict__ cnt01, int E0, int E1, int HB)
{
    int b = blockIdx.x;
    int t = threadIdx.x;
    if (b < HB) {
        int i = b * 256 + t;
        if (i < E0) atomicAdd(&cnt01[dst0[i]], 1);
        else if (i < E0 + E1) atomicAdd(&cnt01[N1 + dst1[i - E0]], 1);
    } else {
        int i = (b - HB) * 256 + t;
        if (i < 256 * 512) {
            int n = i >> 9, k = i & 511;
            float v = (k < HID) ? Ws0[(size_t)k * 256 + n]
                                : Wn0[(size_t)(k - HID) * 256 + n];
            WT0[i] = f2bf(v);
        } else {
            int j = i - 256 * 512;
            int n = j >> 9, k = j & 511;
            float v = (k < HID) ? Ws1[(size_t)k * 128 + n]
                                : Wn1[(size_t)(k - HID) * 128 + n];
            WT1[j] = f2bf(v);
        }
    }
}

// ---------------- 3-phase parallel scan ----------------
// per-256-chunk exclusive scan; totals[b] = chunk sum
__global__ __launch_bounds__(256) void scan_block(
    const int* __restrict__ cnt, int* __restrict__ offs, int* __restrict__ totals)
{
    __shared__ int sh[256];
    int t = threadIdx.x;
    int i = blockIdx.x * 256 + t;
    int v = cnt[i];
    sh[t] = v;
    __syncthreads();
    #pragma unroll
    for (int d = 1; d < 256; d <<= 1) {
        int x = (t >= d) ? sh[t - d] : 0;
        __syncthreads();
        sh[t] += x;
        __syncthreads();
    }
    offs[i] = sh[t] - v;                    // exclusive within chunk
    if (t == 255) totals[blockIdx.x] = sh[t];
}

// single block, 512 threads: in-place exclusive scan of totals[0..nb), nb<=512
__global__ __launch_bounds__(512) void scan_totals(
    int* __restrict__ totals, int nb)
{
    __shared__ int sh[512];
    int t = threadIdx.x;
    int v = (t < nb) ? totals[t] : 0;
    sh[t] = v;
    __syncthreads();
    #pragma unroll
    for (int d = 1; d < 512; d <<= 1) {
        int x = (t >= d) ? sh[t - d] : 0;
        __syncthreads();
        sh[t] += x;
        __syncthreads();
    }
    if (t < nb) totals[t] = sh[t] - v;
}

// offs += chunk base; cursor = offs; sentinel offs[n] = total_edges
__global__ __launch_bounds__(256) void scan_add(
    int* __restrict__ offs, const int* __restrict__ totals,
    int* __restrict__ cursor, int n, int total_edges)
{
    int i = blockIdx.x * 256 + threadIdx.x;
    if (i < n) {
        int v = offs[i] + totals[i >> 8];
        offs[i] = v;
        cursor[i] = v;
    }
    if (i == 0) offs[n] = total_edges;
}

__global__ __launch_bounds__(256) void edge_scatter01(
    const int* __restrict__ src0, const int* __restrict__ dst0,
    const int* __restrict__ src1, const int* __restrict__ dst1,
    const int* __restrict__ node_idx,
    int* __restrict__ cursor, int* __restrict__ edge_rows, int E0, int E1)
{
    int i = blockIdx.x * 256 + threadIdx.x;
    if (i < E0) {
        int pos = atomicAdd(&cursor[dst0[i]], 1);
        edge_rows[pos] = node_idx[src0[i]];
    } else if (i < E0 + E1) {
        int e = i - E0;
        int pos = atomicAdd(&cursor[N1 + dst1[e]], 1);
        edge_rows[pos] = src1[e];
    }
}

// ---------------- gather + mean: one wave per dst, 8-deep MLP ----------------
// SRC_F32: table rows f32[256] (embed); else bf16[256] (h1). Output bf16.
template<bool SRC_F32>
__global__ __launch_bounds__(256) void sage_gather_mean(
    const void* __restrict__ table,
    const int* __restrict__ offs,          // absolute positions
    const int* __restrict__ edge_rows,
    ushort* __restrict__ mean_out,
    int n_dst)
{
    int w = blockIdx.x * 4 + (threadIdx.x >> 6);
    int lane = threadIdx.x & 63;
    if (w >= n_dst) return;
    int beg = offs[w], end = offs[w + 1];
    float a0 = 0.f, a1 = 0.f, a2 = 0.f, a3 = 0.f;
    int e = beg;
    while (e < end) {
        int cnt = end - e; cnt = cnt > 8 ? 8 : cnt;
        int myrow = 0;
        if (lane < cnt) myrow = edge_rows[e + lane];
        f32x4  vf[8];
        ushort4 vh[8];
        #pragma unroll
        for (int j = 0; j < 8; ++j) {
            if (j < cnt) {                       // wave-uniform predicate
                int r = __shfl(myrow, j);
                if (SRC_F32)
                    vf[j] = *((const f32x4*)((const float*)table + (size_t)r * HID) + lane);
                else
                    vh[j] = *((const ushort4*)((const ushort*)table + (size_t)r * HID) + lane);
            }
        }
        #pragma unroll
        for (int j = 0; j < 8; ++j) {
            if (j < cnt) {
                if (SRC_F32) { a0 += vf[j].x; a1 += vf[j].y; a2 += vf[j].z; a3 += vf[j].w; }
                else { a0 += bf2f(vh[j].x); a1 += bf2f(vh[j].y); a2 += bf2f(vh[j].z); a3 += bf2f(vh[j].w); }
            }
        }
        e += cnt;
    }
    float inv = 1.0f / (float)max(end - beg, 1);
    ushort4 o;
    o.x = f2bf(a0 * inv); o.y = f2bf(a1 * inv);
    o.z = f2bf(a2 * inv); o.w = f2bf(a3 * inv);
    *((ushort4*)(mean_out + (size_t)w * HID) + lane) = o;
}

// ---------------- bf16 MFMA fused SAGE GEMM (T14 reg-prefetch) ----------------
// Out[M][BN] = [A_self | A_mean] (M x 512) @ WT^T + bias  (+ReLU)
// BM=64, BN=N_total, BK=64, 4 waves: 1x4 (BN=256) or 2x2 (BN=128).
template<int BN, bool RELU, bool GATHER, bool SELF_F32, bool OUT_BF16>
__global__ __launch_bounds__(256) void sage_gemm_mfma(
    const void* __restrict__ Aself,      // f32 embed (SELF_F32) or bf16 h1
    const int* __restrict__ idx,         // input_nodes (GATHER) or unused
    const ushort* __restrict__ Amean,    // [M][256] bf16
    const ushort* __restrict__ WT,       // [BN][512] bf16
    const float* __restrict__ bias,      // [BN]
    void* __restrict__ Out)              // [M][BN] bf16 or f32
{
    constexpr int BM = 64, BK = 64;
    constexpr int WN = BN / 64;
    constexpr int WM = 4 / WN;
    constexpr int M_FR = (BM / WM) / 16;

    __shared__ __align__(16) ushort As[BM * BK];
    __shared__ __align__(16) ushort Bs[BN * BK];

    const int t = threadIdx.x;
    const int brow = blockIdx.x * BM;
    const int w = t >> 6, l = t & 63;
    const int wc = (w % WN) * 64;
    const int wr = (w / WN) * (BM / WM);
    const int l15 = l & 15, l4 = l >> 4;

    f32x4 acc[M_FR][4] = {};
    f32x4 af[4];
    u16x8 ah[2];
    u16x8 bh[BN / 32];

    auto load_step = [&](int k0) {
        if (SELF_F32 && k0 < HID) {
            #pragma unroll
            for (int i = 0; i < 4; ++i) {
                int li = t + i * 256; int r = li >> 4; int k4 = (li & 15) << 2;
                size_t rg = GATHER ? (size_t)idx[brow + r] : (size_t)(brow + r);
                af[i] = *(const f32x4*)((const float*)Aself + rg * HID + k0 + k4);
            }
        } else {
            #pragma unroll
            for (int i = 0; i < 2; ++i) {
                int li = t + i * 256; int r = li >> 3; int k8 = (li & 7) << 3;
                const ushort* sp;
                if (k0 < HID) {
                    size_t rg = GATHER ? (size_t)idx[brow + r] : (size_t)(brow + r);
                    sp = (const ushort*)Aself + rg * HID + k0 + k8;
                } else {
                    sp = Amean + (size_t)(brow + r) * HID + (k0 - HID) + k8;
                }
                ah[i] = *(const u16x8*)sp;
            }
        }
        #pragma unroll
        for (int i = 0; i < BN / 32; ++i) {
            int li = t + i * 256; int n = li >> 3; int k8 = (li & 7) << 3;
            bh[i] = *(const u16x8*)(WT + (size_t)n * 512 + k0 + k8);
        }
    };

    auto store_step = [&](int k0) {
        if (SELF_F32 && k0 < HID) {
            #pragma unroll
            for (int i = 0; i < 4; ++i) {
                int li = t + i * 256; int r = li >> 4; int k4 = (li & 15) << 2;
                ushort4 h;
                h.x = f2bf(af[i].x); h.y = f2bf(af[i].y);
                h.z = f2bf(af[i].z); h.w = f2bf(af[i].w);
                *(ushort4*)&As[(r * BK + k4) ^ ((r & 7) << 3)] = h;
            }
        } else {
            #pragma unroll
            for (int i = 0; i < 2; ++i) {
                int li = t + i * 256; int r = li >> 3; int k8 = (li & 7) << 3;
                *(u16x8*)&As[(r * BK + k8) ^ ((r & 7) << 3)] = ah[i];
            }
        }
        #pragma unroll
        for (int i = 0; i < BN / 32; ++i) {
            int li = t + i * 256; int n = li >> 3; int k8 = (li & 7) << 3;
            *(u16x8*)&Bs[(n * BK + k8) ^ ((n & 7) << 3)] = bh[i];
        }
    };

    load_step(0);
    store_step(0);
    __syncthreads();

    for (int k0 = 0; k0 < 2 * HID; k0 += BK) {
        int kn = k0 + BK;
        if (kn < 2 * HID) load_step(kn);       // reg prefetch overlaps MFMA

        #pragma unroll
        for (int kk = 0; kk < 2; ++kk) {
            int koff = kk * 32 + l4 * 8;
            bf16x8 a[M_FR], b[4];
            #pragma unroll
            for (int m = 0; m < M_FR; ++m) {
                int r = wr + m * 16 + l15;
                a[m] = *(const bf16x8*)&As[(r * BK + koff) ^ ((r & 7) << 3)];
            }
            #pragma unroll
            for (int n = 0; n < 4; ++n) {
                int c = wc + n * 16 + l15;
                b[n] = *(const bf16x8*)&Bs[(c * BK + koff) ^ ((c & 7) << 3)];
            }
            #pragma unroll
            for (int m = 0; m < M_FR; ++m)
                #pragma unroll
                for (int n = 0; n < 4; ++n)
                    acc[m][n] = __builtin_amdgcn_mfma_f32_16x16x32_bf16(
                        a[m], b[n], acc[m][n], 0, 0, 0);
        }
        __syncthreads();
        if (kn < 2 * HID) store_step(kn);
        __syncthreads();
    }

    // ---- epilogue: D[(l>>4)*4+r][l&15] per frag ----
    #pragma unroll
    for (int m = 0; m < M_FR; ++m) {
        #pragma unroll
        for (int n = 0; n < 4; ++n) {
            int col = wc + n * 16 + l15;
            float bv = bias[col];
            #pragma unroll
            for (int r = 0; r < 4; ++r) {
                int row = brow + wr + m * 16 + l4 * 4 + r;
                float v = acc[m][n][r] + bv;
                if (RELU) v = fmaxf(v, 0.f);
                if (OUT_BF16) ((ushort*)Out)[(size_t)row * BN + col] = f2bf(v);
                else          ((float*)Out)[(size_t)row * BN + col] = v;
            }
        }
    }
}

extern "C" void kernel_launch(void* const* d_in, const int* in_sizes, int n_in,
                              void* d_out, int out_size, void* d_ws, size_t ws_size,
                              hipStream_t stream) {
    const int*   input_nodes = (const int*)d_in[0];
    const int*   src0        = (const int*)d_in[1];
    const int*   dst0        = (const int*)d_in[2];
    const int*   src1        = (const int*)d_in[3];
    const int*   dst1        = (const int*)d_in[4];
    const float* embed       = (const float*)d_in[7];
    const float* W_self0     = (const float*)d_in[8];
    const float* W_neigh0    = (const float*)d_in[9];
    const float* b0          = (const float*)d_in[10];
    const float* W_self1     = (const float*)d_in[11];
    const float* W_neigh1    = (const float*)d_in[12];
    const float* b1          = (const float*)d_in[13];
    float*       out         = (float*)d_out;

    const int E0 = in_sizes[1];          // 1048576
    const int E1 = in_sizes[3];          // 65536

    // -------- workspace layout --------
    char* ws = (char*)d_ws;
    ushort* mean0   = (ushort*)(ws + ((size_t)0  << 20));  // 32 MB bf16
    ushort* h1      = (ushort*)(ws + ((size_t)32 << 20));  // 32 MB bf16
    int*    edges01 = (int*)  (ws + ((size_t)64 << 20));   // ~4.25 MB
    int*    cnt01   = (int*)  (ws + ((size_t)70 << 20));   // 69632 ints (-> cursor)
    int*    offs01  = (int*)  (ws + ((size_t)71 << 20));   // 69633 ints
    int*    tot01   = cnt01 + NC;                           // 272 ints
    ushort* WT0     = (ushort*)(ws + ((size_t)72 << 20));  // 256 KB
    ushort* WT1     = (ushort*)(ws + ((size_t)73 << 20));  // 128 KB
    ushort* mean1   = (ushort*)(ws + ((size_t)74 << 20));  // 2 MB

    // -------- CSR build + weight prep --------
    const int HB = (E0 + E1 + 255) / 256;                  // hist blocks
    hipMemsetAsync(cnt01, 0, (size_t)NC * 4, stream);
    hist_wt<<<HB + 768, 256, 0, stream>>>(
        dst0, dst1, W_self0, W_neigh0, W_self1, W_neigh1,
        WT0, WT1, cnt01, E0, E1, HB);
    scan_block<<<NC / 256, 256, 0, stream>>>(cnt01, offs01, tot01);
    scan_totals<<<1, 512, 0, stream>>>(tot01, NC / 256);
    scan_add<<<NC / 256, 256, 0, stream>>>(offs01, tot01, cnt01, NC, E0 + E1);
    edge_scatter01<<<HB, 256, 0, stream>>>(
        src0, dst0, src1, dst1, input_nodes, cnt01, edges01, E0, E1);

    // ================= layer 0 =================
    sage_gather_mean<true><<<N1 / 4, 256, 0, stream>>>(
        embed, offs01, edges01, mean0, N1);
    sage_gemm_mfma<256, true, true, true, true><<<N1 / 64, 256, 0, stream>>>(
        embed, input_nodes, mean0, WT0, b0, h1);

    // ================= layer 1 =================
    sage_gather_mean<false><<<N2 / 4, 256, 0, stream>>>(
        h1, offs01 + N1, edges01, mean1, N2);
    sage_gemm_mfma<128, false, false, false, false><<<N2 / 64, 256, 0, stream>>>(
        h1, nullptr, mean1, WT1, b1, out);
}